// Round 7
// baseline (337.331 us; speedup 1.0000x reference)
//
#include <hip/hip_runtime.h>

#define TSTEPS 128
#define NIN 24
#define HD 128
#define BT 16
#define NBLK 128     // 2048 / BT
#define NTH 1024     // 16 waves: 0-7 = layer-0 role, 8-15 = layer-1 role

// LDS geometry (units: _Float16 elements)
// h panels: [batch 16][hidden 128], row stride RS=136 (16B-aligned rows).
#define RS    136
#define SLOT  (BT*RS)          // 2176
#define H1B   (3*SLOT)         // h0 TRIPLE buffer (lag-2 slack), then h1 double
#define W1B   (5*SLOT)         // whh1 fragment panel: 8 groups * 16 frags * 512
#define SM_ELTS (W1B + 65536)  // 76416 f16
#define SM_BYTES (SM_ELTS*2)   // 152832 B (dynamic LDS, 1 block/CU)

typedef _Float16 half8  __attribute__((ext_vector_type(8)));
typedef _Float16 half4v __attribute__((ext_vector_type(4)));
typedef float    floatx4 __attribute__((ext_vector_type(4)));

__device__ __forceinline__ float sigf(float x) {
    return __builtin_amdgcn_rcpf(1.0f + __expf(-x));
}
__device__ __forceinline__ float tanh_f(float x) {
    return 1.0f - 2.0f * __builtin_amdgcn_rcpf(1.0f + __expf(2.0f * x));
}

__device__ __forceinline__ half8 ldw8(const float* p) {
    const float4* q = (const float4*)p;
    float4 a = q[0], b = q[1];
    half8 r;
    r[0] = (_Float16)a.x; r[1] = (_Float16)a.y; r[2] = (_Float16)a.z; r[3] = (_Float16)a.w;
    r[4] = (_Float16)b.x; r[5] = (_Float16)b.y; r[6] = (_Float16)b.z; r[7] = (_Float16)b.w;
    return r;
}

// LDS-only barrier: drain own ds ops, sync, don't drain vmcnt (global x
// prefetch loads span barriers, T4-style).
__device__ __forceinline__ void barrier_lgkm() {
    asm volatile("s_waitcnt lgkmcnt(0)" ::: "memory");
    __builtin_amdgcn_s_barrier();
    __builtin_amdgcn_sched_barrier(0);
}

// =====================================================================
// Fused 2-layer LSTM, one block per 16-row batch tile, wave-role split
// (waves 0-7 = layer 0, waves 8-15 = layer 1) with a LAG-2 PHASE-SPLIT
// schedule for layer 1:
//   iter t: L0 computes h0[t].
//           L1 post-phase: h1[t-2] = gates(P_held + whh1*h1[t-3])
//           L1 pre-phase : P_next  = bias1 + wih1*h0[t-1]   (1-barrier-old
//                          input -> runs in the LDS-quiet shadow while L0
//                          is in its trans tail)
// One barrier per iter (130 total, uniform across roles). h0 is triple-
// buffered (slot t%3), h1 parity double-buffered. Accumulation order is
// identical to round 6 -> bit-identical results.
// Transposed MFMA orientation (A=weights, B=h^T): lane (qd,nn) holds gate
// rows hw*16+qd*4+r, batch col nn; h-write is one ds_write_b64. Layer-0
// bias folded into the x-MFMA via a constant-1 x column.
// =====================================================================
__global__ __launch_bounds__(NTH, 4)
void lstm2_fused(const float* __restrict__ x,
                 const float* __restrict__ Wih0, const float* __restrict__ Whh0,
                 const float* __restrict__ bih0, const float* __restrict__ bhh0,
                 const float* __restrict__ Wih1, const float* __restrict__ Whh1,
                 const float* __restrict__ bih1, const float* __restrict__ bhh1,
                 const float* __restrict__ Wfc,  const float* __restrict__ bfc,
                 float* __restrict__ out)
{
    extern __shared__ __align__(16) _Float16 SM[];

    const int tid = threadIdx.x;
    const int blk = blockIdx.x;
    const int wv  = tid >> 6;
    const int ln  = tid & 63;
    const int qd  = ln >> 4;
    const int nn  = ln & 15;
    const int b0  = blk * BT;

    const half8 z8 = {0, 0, 0, 0, 0, 0, 0, 0};
    const floatx4 zf4 = {0.f, 0.f, 0.f, 0.f};

    // ---- common prologue: zero h panels, stage whh1 panel (all 16 waves) ----
    for (int i = tid * 8; i < W1B; i += NTH * 8) *(half8*)&SM[i] = z8;
    // whh1 -> LDS in MFMA A-fragment order:
    // frag (hw_,tI,kk) at W1B + (hw_*16 + tI*4 + kk)*512 + (qd*16+nn)*8 + e
    for (int i = tid; i < 512 * 32; i += NTH) {
        int g  = i >> 5;
        int k0 = (i & 31) << 2;
        float4 v = *(const float4*)(Whh1 + g * HD + k0);
        half4v h; h[0] = (_Float16)v.x; h[1] = (_Float16)v.y;
                  h[2] = (_Float16)v.z; h[3] = (_Float16)v.w;
        int dst = W1B + ((((g >> 4) & 7) * 16) + (g >> 7) * 4 + (k0 >> 5)) * 512
                      + (((k0 >> 3) & 3) * 16 + (g & 15)) * 8 + (k0 & 7);
        *(half4v*)&SM[dst] = h;
    }

    if (wv < 8) {
        // ================= ROLE L0: layer 0, hidden cols wv*16..+16 =================
        const int hw_  = wv;
        const int hcol = hw_ * 16 + qd * 4;

        half8 wih0[4];           // bias folded at qd==3 via constant-1 x col
        half8 whh0[4][4];
#pragma unroll
        for (int tI = 0; tI < 4; ++tI) {
            int g = tI * HD + hw_ * 16 + nn;
            if (qd < 3) {
                wih0[tI] = ldw8(Wih0 + g * NIN + qd * 8);
            } else {
                wih0[tI] = z8;
                wih0[tI][0] = (_Float16)(bih0[g] + bhh0[g]);
            }
#pragma unroll
            for (int kk = 0; kk < 4; ++kk)
                whh0[tI][kk] = ldw8(Whh0 + g * HD + kk * 32 + qd * 8);
        }

        const float* xrow = x + (size_t)(b0 + nn) * (TSTEPS * NIN) + (qd < 3 ? qd * 8 : 0);
        float4 pf0 = *(const float4*)(xrow);
        float4 pf1 = *(const float4*)(xrow + 4);

        float cs0[4] = {0.f, 0.f, 0.f, 0.f};
        int wr3 = 0, p3 = 2;     // wr3 = t%3 (write slot), p3 = (t-1)%3 (read slot)

        __syncthreads();   // prologue barrier: zeros + whh1 panel staged

#pragma unroll 1
        for (int t = 0; t < 130; ++t) {
            if (t < TSTEPS) {
                half8 ax;
                if (qd < 3) {
                    ax[0] = (_Float16)pf0.x; ax[1] = (_Float16)pf0.y; ax[2] = (_Float16)pf0.z; ax[3] = (_Float16)pf0.w;
                    ax[4] = (_Float16)pf1.x; ax[5] = (_Float16)pf1.y; ax[6] = (_Float16)pf1.z; ax[7] = (_Float16)pf1.w;
                } else {
                    ax = z8; ax[0] = (_Float16)1.0f;
                }
                {
                    const int tn = (t < TSTEPS - 1) ? t + 1 : TSTEPS - 1;
                    pf0 = *(const float4*)(xrow + (size_t)tn * NIN);
                    pf1 = *(const float4*)(xrow + (size_t)tn * NIN + 4);
                }

                floatx4 acc0[4];
#pragma unroll
                for (int tI = 0; tI < 4; ++tI)
                    acc0[tI] = __builtin_amdgcn_mfma_f32_16x16x32_f16(wih0[tI], ax, zf4, 0, 0, 0);

                if (t > 0) {
                    __builtin_amdgcn_s_setprio(1);
#pragma unroll
                    for (int kk = 0; kk < 4; ++kk) {
                        const half8 ah = *(const half8*)&SM[p3 * SLOT + nn * RS + kk * 32 + qd * 8];
#pragma unroll
                        for (int tI = 0; tI < 4; ++tI)
                            acc0[tI] = __builtin_amdgcn_mfma_f32_16x16x32_f16(whh0[tI][kk], ah, acc0[tI], 0, 0, 0);
                    }
                    __builtin_amdgcn_s_setprio(0);
                }

                half4v hw;
#pragma unroll
                for (int r = 0; r < 4; ++r) {
                    float iv = sigf(acc0[0][r]);
                    float fv = sigf(acc0[1][r]);
                    float gv = tanh_f(acc0[2][r]);
                    float ov = sigf(acc0[3][r]);
                    float cn = (t > 0 ? fv * cs0[r] : 0.f) + iv * gv;
                    cs0[r] = cn;
                    hw[r] = (_Float16)(ov * tanh_f(cn));
                }
                *(half4v*)&SM[wr3 * SLOT + nn * RS + hcol] = hw;
            }
            p3 = wr3;
            wr3 = (wr3 == 2) ? 0 : wr3 + 1;
            barrier_lgkm();
        }
    } else {
        // ================= ROLE L1: layer 1, hidden cols (wv-8)*16..+16 =================
        const int hw_  = wv - 8;
        const int hcol = hw_ * 16 + qd * 4;

        floatx4 bias1[4];
        half8 wih1[4][4];
#pragma unroll
        for (int tI = 0; tI < 4; ++tI) {
#pragma unroll
            for (int r = 0; r < 4; ++r)
                bias1[tI][r] = bih1[tI * HD + hcol + r] + bhh1[tI * HD + hcol + r];
            int g = tI * HD + hw_ * 16 + nn;
#pragma unroll
            for (int kk = 0; kk < 4; ++kk)
                wih1[tI][kk] = ldw8(Wih1 + g * HD + kk * 32 + qd * 8);
        }
        const int w1base = W1B + hw_ * 8192 + ln * 8;

        float cs1[4] = {0.f, 0.f, 0.f, 0.f};
        floatx4 pAcc[4];         // P = bias1 + wih1*h0[t-1], held across the barrier
        int wr3 = 0, p3 = 2;     // p3 = (t-1)%3: h0 slot for the pre-phase

        __syncthreads();   // prologue barrier

#pragma unroll 1
        for (int t = 0; t < 130; ++t) {
            // ---- post-phase: finish h1[t-2] = gates(P + whh1*h1[t-3]) ----
            if (t >= 2) {
                const int h1r = H1B + ((t + 1) & 1) * SLOT;   // h1[t-3]
                const int h1w = H1B + (t & 1) * SLOT;         // h1[t-2]

                __builtin_amdgcn_s_setprio(1);
#pragma unroll
                for (int kk = 0; kk < 4; ++kk) {
                    const half8 a2 = *(const half8*)&SM[h1r + nn * RS + kk * 32 + qd * 8];
#pragma unroll
                    for (int tI = 0; tI < 4; ++tI) {
                        const half8 w1 = *(const half8*)&SM[w1base + (tI * 4 + kk) * 512];
                        pAcc[tI] = __builtin_amdgcn_mfma_f32_16x16x32_f16(w1, a2, pAcc[tI], 0, 0, 0);
                    }
                }
                __builtin_amdgcn_s_setprio(0);

                half4v hw;
#pragma unroll
                for (int r = 0; r < 4; ++r) {
                    float iv = sigf(pAcc[0][r]);
                    float fv = sigf(pAcc[1][r]);
                    float gv = tanh_f(pAcc[2][r]);
                    float ov = sigf(pAcc[3][r]);
                    float cn = fv * cs1[r] + iv * gv;
                    cs1[r] = cn;
                    hw[r] = (_Float16)(ov * tanh_f(cn));
                }
                *(half4v*)&SM[h1w + nn * RS + hcol] = hw;
            }

            // ---- pre-phase: P = bias1 + wih1*h0[t-1] (input one barrier old) ----
            if (t >= 1 && t <= 128) {
#pragma unroll
                for (int kk = 0; kk < 4; ++kk) {
                    const half8 ah = *(const half8*)&SM[p3 * SLOT + nn * RS + kk * 32 + qd * 8];
#pragma unroll
                    for (int tI = 0; tI < 4; ++tI)
                        pAcc[tI] = __builtin_amdgcn_mfma_f32_16x16x32_f16(
                            wih1[tI][kk], ah, (kk == 0 ? bias1[tI] : pAcc[tI]), 0, 0, 0);
                }
            }
            p3 = wr3;
            wr3 = (wr3 == 2) ? 0 : wr3 + 1;
            barrier_lgkm();
        }
    }

    // =============== FC head: h1[127] in h1 slot 1 (written at iter 129) ===============
    if (tid < 512) {
        int b = tid >> 5, sub = tid & 31;
        const _Float16* hp = &SM[H1B + SLOT + b * RS + sub * 4];
        const float4 wv4 = *(const float4*)(Wfc + sub * 4);
        float s = (float)hp[0] * wv4.x + (float)hp[1] * wv4.y
                + (float)hp[2] * wv4.z + (float)hp[3] * wv4.w;
        s += __shfl_down(s, 16, 32);
        s += __shfl_down(s, 8, 32);
        s += __shfl_down(s, 4, 32);
        s += __shfl_down(s, 2, 32);
        s += __shfl_down(s, 1, 32);
        if (sub == 0) out[b0 + b] = s + bfc[0];
    }
}

extern "C" void kernel_launch(void* const* d_in, const int* in_sizes, int n_in,
                              void* d_out, int out_size, void* d_ws, size_t ws_size,
                              hipStream_t stream) {
    static bool attr_set = false;
    if (!attr_set) {
        hipFuncSetAttribute(reinterpret_cast<const void*>(&lstm2_fused),
                            hipFuncAttributeMaxDynamicSharedMemorySize, SM_BYTES);
        attr_set = true;
    }
    const float* x    = (const float*)d_in[0];
    const float* Wih0 = (const float*)d_in[1];
    const float* Whh0 = (const float*)d_in[2];
    const float* bih0 = (const float*)d_in[3];
    const float* bhh0 = (const float*)d_in[4];
    const float* Wih1 = (const float*)d_in[5];
    const float* Whh1 = (const float*)d_in[6];
    const float* bih1 = (const float*)d_in[7];
    const float* bhh1 = (const float*)d_in[8];
    const float* Wfc  = (const float*)d_in[9];
    const float* bfc  = (const float*)d_in[10];
    float* out = (float*)d_out;

    lstm2_fused<<<dim3(NBLK), dim3(NTH), SM_BYTES, stream>>>(
        x, Wih0, Whh0, bih0, bhh0, Wih1, Whh1, bih1, bhh1, Wfc, bfc, out);
}